// Round 10
// baseline (267.896 us; speedup 1.0000x reference)
//
#include <hip/hip_runtime.h>

#define TT 512
#define DD 16
#define HH 30
#define LL 10
#define C  4                  // timesteps per phase
#define TCH (TT / C)          // 128 chunks
#define PH (TCH + LL - 1)     // 137 phases
#define WRH 40                // halfs per batch-row (80 B): 32 data + pad
#define GRP 16                // batches per block = MFMA N
#define BLOCKT (LL * 64)      // 640 threads, wave = layer

typedef _Float16 f16x8 __attribute__((ext_vector_type(8)));
typedef _Float16 h2    __attribute__((ext_vector_type(2)));
typedef float    f32x4 __attribute__((ext_vector_type(4)));

union U128 { uint4 u; f16x8 h; };

// act block offset in halfs: [par][destLayer-1][cc] -> [GRP][WRH]
#define ACTOFF(par, lm1, cc) ((((par) * (LL - 1) + (lm1)) * C + (cc)) * (GRP * WRH))

// ---- trans-free tanh, packed f16 Pade(5,4) ----
// tanh(x) ~= x(s^2+105s+945)/(15s^2+420s+945), s=x^2, x clamped to +-3.75.
// Max approx error ~1.8e-3 (boundary); no v_exp/v_rcp: division via packed
// magic-seed (0x7799 per half; den in [945,15600] so no cross-half borrow)
// + 2 packed-Newton iterations. All ops are full-rate v_pk_* / VALU.
__device__ __forceinline__ h2 tanh_pk(float lo, float hi) {
    const float xl = fminf(fmaxf(lo, -3.75f), 3.75f);
    const float xh = fminf(fmaxf(hi, -3.75f), 3.75f);
#if __has_builtin(__builtin_amdgcn_cvt_pkrtz)
    const h2 x = (h2)__builtin_amdgcn_cvt_pkrtz(xl, xh);
#else
    h2 x; x[0] = (_Float16)xl; x[1] = (_Float16)xh;
#endif
    const h2 s    = x * x;
    const h2 c945 = {(_Float16)945.f, (_Float16)945.f};
    h2 t = s + (h2){(_Float16)105.f, (_Float16)105.f};
    t = t * s + c945;                                  // s^2 + 105 s + 945
    h2 u = s * (h2){(_Float16)15.f, (_Float16)15.f}
             + (h2){(_Float16)420.f, (_Float16)420.f};
    u = u * s + c945;                                  // 15 s^2 + 420 s + 945
    union { h2 h; unsigned v; } du, yu;
    du.h = u;
    yu.v = 0x77997799u - du.v;                         // packed rcp seed
    h2 y = yu.h;
    const h2 c2 = {(_Float16)2.f, (_Float16)2.f};
    y = y * (c2 - u * y);                              // Newton 1
    y = y * (c2 - u * y);                              // Newton 2
    return (x * t) * y;
}

// Raw pipeline barrier: drain LDS ops only; global prefetch stays in flight.
__device__ __forceinline__ void pipe_barrier() {
    __builtin_amdgcn_sched_barrier(0);
    asm volatile("s_waitcnt lgkmcnt(0)" ::: "memory");
    __builtin_amdgcn_sched_barrier(0);
    __builtin_amdgcn_s_barrier();
    __builtin_amdgcn_sched_barrier(0);
    asm volatile("" ::: "memory");
}

// storage k-position <-> natural neuron index permutation.
// Chosen so a lane's D-fragment {16t+4qq+r} lands at positions 8qq+4t+r:
// the MFMA output IS the next step's B-own fragment -- state stays in VGPRs.
__device__ __forceinline__ int nu_of(int k) {
    return 16 * ((k >> 2) & 1) + 4 * (k >> 3) + (k & 3);
}

__global__ __launch_bounds__(BLOCKT) void rnn_mfma4(
    const float* __restrict__ x,   const float* __restrict__ wi0,
    const float* __restrict__ wih, const float* __restrict__ whh,
    const float* __restrict__ bih, const float* __restrict__ bhh,
    const float* __restrict__ fcw, const float* __restrict__ fcb,
    float* __restrict__ out)
{
    extern __shared__ __align__(16) _Float16 act[];  // [2][LL-1][C][GRP][WRH]

    const int tid  = threadIdx.x;
    const int l    = tid >> 6;        // wave == layer
    const int lane = tid & 63;
    const int n    = lane & 15;       // batch-in-group (B col / D col / A m-row)
    const int qq   = lane >> 4;       // k-slice group / D row-group
    const int b0   = blockIdx.x * GRP;

    // ---- A-frags. A[m][k]: m = 16*tile + n, k-position kap = 8*qq + i;
    //      column = neuron nu_of(kap) (permuted), except layer-0 x (natural).
    f16x8 wain[2], waown[2];
    #pragma unroll
    for (int tile = 0; tile < 2; ++tile) {
        const int j = 16 * tile + n;
        #pragma unroll
        for (int i = 0; i < 8; ++i) {
            const int kap = 8 * qq + i;
            const int nu  = nu_of(kap);
            float vi = 0.f, vo = 0.f;
            if (j < HH) {
                if (l == 0) { if (kap < DD) vi = wi0[j * DD + kap]; }
                else        { if (nu  < HH) vi = wih[(l - 1) * 900 + j * HH + nu]; }
                if (nu < HH) vo = whh[l * 900 + j * HH + nu];
            }
            wain[tile][i]  = (_Float16)vi;
            waown[tile][i] = (_Float16)vo;
        }
    }
    // ---- bias as MFMA C-init; D row j2 = 16*tile + 4*qq + r (natural) ----
    f32x4 cb[2];
    #pragma unroll
    for (int tile = 0; tile < 2; ++tile)
        #pragma unroll
        for (int r = 0; r < 4; ++r) {
            const int j2 = 16 * tile + 4 * qq + r;
            cb[tile][r] = (j2 < HH) ? bih[l * HH + j2] + bhh[l * HH + j2] : 0.f;
        }
    // ---- FC weights in this lane's bown layout: i -> neuron nu_of(8qq+i) ----
    float fcl[8];
    #pragma unroll
    for (int i = 0; i < 8; ++i) {
        const int nu = nu_of(8 * qq + i);
        fcl[i] = (nu < HH) ? fcw[nu] : 0.f;
    }
    const float fbv = fcb[0];

    // ---- wave-0 x prefetch: xb[cc] = x[b0+n][t=chunk*C+cc][8qq..8qq+7] ----
    float4 xb[C][2];
    const float4* x4 = (const float4*)x;
    const size_t xbase = (size_t)(b0 + n) * TT * 4;
    if (l == 0 && qq < 2) {
        #pragma unroll
        for (int cc = 0; cc < C; ++cc) {
            xb[cc][0] = x4[xbase + cc * 4 + 2 * qq];
            xb[cc][1] = x4[xbase + cc * 4 + 2 * qq + 1];
        }
    }

    // recurrent state, register-resident: h(-1) = 0
    f16x8 bown;
    #pragma unroll
    for (int i = 0; i < 8; ++i) bown[i] = (_Float16)0.f;

    __syncthreads();   // once, pre-loop (no LDS init needed; phase alignment)

    for (int p = 0; p < PH; ++p) {
        const int pt = p - l;         // this wave's chunk index
        const int q  = (p + 1) & 1;   // read parity
        const int wp = p & 1;         // write parity

        if (0 <= pt && pt < TCH) {
            // ---- stage all C input fragments (one lgkm wait, off-chain) ----
            U128 binu[C];
            if (l == 0) {
                #pragma unroll
                for (int cc = 0; cc < C; ++cc) {
                    if (qq < 2) {
                        const float4 u = xb[cc][0], v = xb[cc][1];
                        binu[cc].h[0] = (_Float16)u.x; binu[cc].h[1] = (_Float16)u.y;
                        binu[cc].h[2] = (_Float16)u.z; binu[cc].h[3] = (_Float16)u.w;
                        binu[cc].h[4] = (_Float16)v.x; binu[cc].h[5] = (_Float16)v.y;
                        binu[cc].h[6] = (_Float16)v.z; binu[cc].h[7] = (_Float16)v.w;
                        if (p + 1 < TCH) {   // refill this slot for next chunk
                            const int tn = (p + 1) * C + cc;
                            xb[cc][0] = x4[xbase + tn * 4 + 2 * qq];
                            xb[cc][1] = x4[xbase + tn * 4 + 2 * qq + 1];
                        }
                    } else {
                        binu[cc].u = uint4{0u, 0u, 0u, 0u};
                    }
                }
            } else {
                #pragma unroll
                for (int cc = 0; cc < C; ++cc)
                    binu[cc].u = *(const uint4*)(act + ACTOFF(q, l - 1, cc)
                                                 + n * WRH + 8 * qq);
            }

            // ---- input-side MFMAs for all C steps: independent, issue early ----
            f32x4 dp0[C], dp1[C];
            #pragma unroll
            for (int cc = 0; cc < C; ++cc) {
                dp0[cc] = __builtin_amdgcn_mfma_f32_16x16x32_f16(wain[0], binu[cc].h, cb[0], 0, 0, 0);
                dp1[cc] = __builtin_amdgcn_mfma_f32_16x16x32_f16(wain[1], binu[cc].h, cb[1], 0, 0, 0);
            }

            // ---- serial own-chain: mfma -> tanh -> pack, state in VGPRs ----
            #pragma unroll
            for (int cc = 0; cc < C; ++cc) {
                const f32x4 d0 = __builtin_amdgcn_mfma_f32_16x16x32_f16(waown[0], bown, dp0[cc], 0, 0, 0);
                const f32x4 d1 = __builtin_amdgcn_mfma_f32_16x16x32_f16(waown[1], bown, dp1[cc], 0, 0, 0);
                const h2 p0 = tanh_pk(d0[0], d0[1]);
                const h2 p1 = tanh_pk(d0[2], d0[3]);
                const h2 p2 = tanh_pk(d1[0], d1[1]);
                const h2 p3 = tanh_pk(d1[2], d1[3]);
                f16x8 nb;
                nb[0] = p0[0]; nb[1] = p0[1]; nb[2] = p1[0]; nb[3] = p1[1];
                nb[4] = p2[0]; nb[5] = p2[1]; nb[6] = p3[0]; nb[7] = p3[1];
                bown = nb;
                if (l < LL - 1) {    // handoff: contiguous b128, kpos order
                    U128 w; w.h = nb;
                    *(uint4*)(act + ACTOFF(wp, l, cc) + n * WRH + 8 * qq) = w.u;
                }
            }
        }
        pipe_barrier();               // lgkm drain only; vmem stays in flight
    }

    // ---- FC on h_9(T-1), register-resident in wave 9's bown ----
    if (l == LL - 1) {
        float v = 0.f;
        #pragma unroll
        for (int i = 0; i < 8; ++i) v = fmaf((float)bown[i], fcl[i], v);
        v += __shfl_xor(v, 16);      // combine the four qq k-slices
        v += __shfl_xor(v, 32);
        if (qq == 0) out[b0 + n] = v + fbv;
    }
}

extern "C" void kernel_launch(void* const* d_in, const int* in_sizes, int n_in,
                              void* d_out, int out_size, void* d_ws, size_t ws_size,
                              hipStream_t stream) {
    const float* x   = (const float*)d_in[0];
    const float* wi0 = (const float*)d_in[1];
    const float* wih = (const float*)d_in[2];
    const float* whh = (const float*)d_in[3];
    const float* bih = (const float*)d_in[4];
    const float* bhh = (const float*)d_in[5];
    const float* fcw = (const float*)d_in[6];
    const float* fcb = (const float*)d_in[7];
    float* out = (float*)d_out;

    const size_t lds_bytes =
        (size_t)(2 * (LL - 1) * C * GRP * WRH) * sizeof(_Float16); // 92160 B
    hipFuncSetAttribute((const void*)rnn_mfma4,
                        hipFuncAttributeMaxDynamicSharedMemorySize,
                        (int)lds_bytes);

    rnn_mfma4<<<1024 / GRP, BLOCKT, lds_bytes, stream>>>(x, wi0, wih, whh,
                                                         bih, bhh, fcw, fcb, out);
}